// Round 1
// baseline (673.957 us; speedup 1.0000x reference)
//
#include <hip/hip_runtime.h>

// Problem constants (fixed by reference)
#define BATCH 64
#define DIM 256
#define HW 1024            // 32*32
#define N_POS 65536        // BATCH*HW
#define K_CODES 1024
#define NTOT 16777216      // BATCH*DIM*HW

// Tiling for the score GEMM
#define TP 128             // positions per block
#define TK 128             // codes per k-tile
#define DC 32              // d-chunk
#define PADW 132           // padded LDS row width (132%4==0 keeps 16B align, %32==4 breaks bank stride)

// ---------------------------------------------------------------------------
// Kernel 0: cnorm[k] = 0.5 * ||codebook[k]||^2
// One wave per row: 64 lanes x float4 = 256 floats.
__global__ void cnorm_kernel(const float* __restrict__ cb, float* __restrict__ cnorm) {
    const int wave = threadIdx.x >> 6;
    const int lane = threadIdx.x & 63;
    const int row = blockIdx.x * 4 + wave;          // grid 256 -> rows 0..1023
    const float4 v = *reinterpret_cast<const float4*>(cb + row * DIM + lane * 4);
    float s = v.x * v.x + v.y * v.y + v.z * v.z + v.w * v.w;
    #pragma unroll
    for (int off = 32; off; off >>= 1) s += __shfl_xor(s, off);
    if (lane == 0) cnorm[row] = 0.5f * s;
}

// ---------------------------------------------------------------------------
// Kernel 1: for each position n, idx[n] = argmax_k (x_n . c_k - 0.5||c_k||^2)
// == argmin_k ||x_n - c_k||^2 with first-min (smallest k) tie-breaking.
// Block: 256 threads, 128 positions x all 1024 codes. 8x8 register blocking.
__global__ __launch_bounds__(256, 3) void argmin_kernel(
        const float* __restrict__ x, const float* __restrict__ cb,
        const float* __restrict__ cnorm, int* __restrict__ idx_out) {
    __shared__ float xs[DC][PADW];     // xs[dd][p]  = x[b][d0+dd][p0+p]
    __shared__ float cs[DC][PADW];     // cs[dd][kk] = cb[k0+kk][d0+dd]
    __shared__ float redv[TP][16];
    __shared__ int   redi[TP][16];

    const int tid = threadIdx.x;
    const int n0 = blockIdx.x * TP;    // grid 512
    const int b  = n0 >> 10;
    const int p0 = n0 & 1023;
    const float* xb = x + (size_t)b * DIM * HW + p0;

    const int r = tid >> 4;            // 0..15  -> positions r*8..r*8+7
    const int c = tid & 15;            // 0..15  -> codes    c*8..c*8+7 (within k-tile)

    float bestv[8];
    int   besti[8];
    #pragma unroll
    for (int i = 0; i < 8; ++i) { bestv[i] = -3.0e38f; besti[i] = 0; }

    for (int kt = 0; kt < K_CODES / TK; ++kt) {
        const int k0 = kt * TK;
        float acc[8][8];
        #pragma unroll
        for (int i = 0; i < 8; ++i)
            #pragma unroll
            for (int j = 0; j < 8; ++j) acc[i][j] = 0.0f;

        for (int dc = 0; dc < DIM / DC; ++dc) {
            const int d0 = dc * DC;
            __syncthreads();   // previous iteration's LDS reads done
            // Stage x tile: 32 rows(dd) x 128 positions; thread loads 4 consecutive float4.
            #pragma unroll
            for (int q = 0; q < 4; ++q) {
                const int f  = tid * 4 + q;     // float4 index in [0,1024)
                const int dd = f >> 5;          // row (32 float4 per row)
                const int p4 = f & 31;
                const float4 v = *reinterpret_cast<const float4*>(
                    xb + (size_t)(d0 + dd) * HW + p4 * 4);
                *reinterpret_cast<float4*>(&xs[dd][p4 * 4]) = v;
            }
            // Stage codebook tile transposed: cs[dd][kk] = cb[k0+kk][d0+dd]
            #pragma unroll
            for (int q = 0; q < 4; ++q) {
                const int f  = tid * 4 + q;     // float4 index in [0,1024)
                const int kk = f >> 3;          // 8 float4 per codebook row chunk
                const int d4 = f & 7;
                const float4 v = *reinterpret_cast<const float4*>(
                    cb + (size_t)(k0 + kk) * DIM + d0 + d4 * 4);
                cs[d4 * 4 + 0][kk] = v.x;
                cs[d4 * 4 + 1][kk] = v.y;
                cs[d4 * 4 + 2][kk] = v.z;
                cs[d4 * 4 + 3][kk] = v.w;
            }
            __syncthreads();
            #pragma unroll
            for (int dd = 0; dd < DC; ++dd) {
                float xr[8], cr[8];
                *reinterpret_cast<float4*>(&xr[0]) = *reinterpret_cast<const float4*>(&xs[dd][r * 8]);
                *reinterpret_cast<float4*>(&xr[4]) = *reinterpret_cast<const float4*>(&xs[dd][r * 8 + 4]);
                *reinterpret_cast<float4*>(&cr[0]) = *reinterpret_cast<const float4*>(&cs[dd][c * 8]);
                *reinterpret_cast<float4*>(&cr[4]) = *reinterpret_cast<const float4*>(&cs[dd][c * 8 + 4]);
                #pragma unroll
                for (int i = 0; i < 8; ++i)
                    #pragma unroll
                    for (int j = 0; j < 8; ++j)
                        acc[i][j] = fmaf(xr[i], cr[j], acc[i][j]);
            }
        }
        // Epilogue for this k-tile: score = dot - cnorm; keep per-row best.
        #pragma unroll
        for (int j = 0; j < 8; ++j) {
            const int k = k0 + c * 8 + j;       // ascending k per thread
            const float cn = cnorm[k];
            #pragma unroll
            for (int i = 0; i < 8; ++i) {
                const float s = acc[i][j] - cn;
                if (s > bestv[i]) { bestv[i] = s; besti[i] = k; }  // strict > keeps first min
            }
        }
    }

    __syncthreads();
    #pragma unroll
    for (int i = 0; i < 8; ++i) {
        redv[r * 8 + i][c] = bestv[i];
        redi[r * 8 + i][c] = besti[i];
    }
    __syncthreads();
    if (tid < TP) {
        float bv = redv[tid][0];
        int   bi = redi[tid][0];
        #pragma unroll
        for (int c2 = 1; c2 < 16; ++c2) {
            const float v  = redv[tid][c2];
            const int   iv = redi[tid][c2];
            if (v > bv || (v == bv && iv < bi)) { bv = v; bi = iv; }
        }
        idx_out[n0 + tid] = bi;
    }
}

// ---------------------------------------------------------------------------
// Kernel 2: out[b][d][p] = cb[idx[n]][d]; partial[blk] = sum (x - q)^2 over tile
// Block: 256 threads = 4 waves; 64 positions; wave w handles d in [w*64, w*64+64).
__global__ __launch_bounds__(256) void quantize_kernel(
        const float* __restrict__ x, const float* __restrict__ cb,
        const int* __restrict__ idx, float* __restrict__ out,
        float* __restrict__ partial) {
    const int blk = blockIdx.x;        // grid 1024
    const int n0 = blk * 64;
    const int b  = n0 >> 10;
    const int p0 = n0 & 1023;
    const int lane = threadIdx.x & 63;
    const int w    = threadIdx.x >> 6;
    const int ci = idx[n0 + lane];
    const float4* cbrow4 = reinterpret_cast<const float4*>(cb + (size_t)ci * DIM);
    const size_t base = (size_t)b * DIM * HW + p0 + lane;

    float s = 0.0f;
    #pragma unroll
    for (int dq = 0; dq < 16; ++dq) {
        const float4 cq = cbrow4[w * 16 + dq];
        const int dbase = w * 64 + dq * 4;
        const float qv[4] = {cq.x, cq.y, cq.z, cq.w};
        #pragma unroll
        for (int e = 0; e < 4; ++e) {
            const int d = dbase + e;
            const float xv = x[base + (size_t)d * HW];
            out[base + (size_t)d * HW] = qv[e];
            const float diff = xv - qv[e];
            s = fmaf(diff, diff, s);
        }
    }
    #pragma unroll
    for (int off = 32; off; off >>= 1) s += __shfl_xor(s, off);
    __shared__ float wsum[4];
    if (lane == 0) wsum[w] = s;
    __syncthreads();
    if (threadIdx.x == 0) partial[blk] = wsum[0] + wsum[1] + wsum[2] + wsum[3];
}

// ---------------------------------------------------------------------------
// Kernel 3: loss = 1.25 * sum(partial) / NTOT   (codebook + 0.25*commitment)
__global__ void finalize_kernel(const float* __restrict__ partial, float* __restrict__ out_loss) {
    float s = 0.0f;
    for (int i = threadIdx.x; i < 1024; i += 256) s += partial[i];
    #pragma unroll
    for (int off = 32; off; off >>= 1) s += __shfl_xor(s, off);
    __shared__ float wsum[4];
    if ((threadIdx.x & 63) == 0) wsum[threadIdx.x >> 6] = s;
    __syncthreads();
    if (threadIdx.x == 0)
        out_loss[0] = 1.25f * (wsum[0] + wsum[1] + wsum[2] + wsum[3]) / (float)NTOT;
}

// ---------------------------------------------------------------------------
extern "C" void kernel_launch(void* const* d_in, const int* in_sizes, int n_in,
                              void* d_out, int out_size, void* d_ws, size_t ws_size,
                              hipStream_t stream) {
    const float* x  = (const float*)d_in[0];   // [64,256,32,32]
    const float* cb = (const float*)d_in[1];   // [1024,256]
    float* out = (float*)d_out;                // [16777216 quantized] + [1 loss]

    // ws layout: idx[65536] ints | partial[1024] floats | cnorm[1024] floats
    int*   idx     = (int*)d_ws;
    float* partial = (float*)((char*)d_ws + 262144);
    float* cnorm   = (float*)((char*)d_ws + 262144 + 4096);

    cnorm_kernel<<<dim3(256), dim3(256), 0, stream>>>(cb, cnorm);
    argmin_kernel<<<dim3(512), dim3(256), 0, stream>>>(x, cb, cnorm, idx);
    quantize_kernel<<<dim3(1024), dim3(256), 0, stream>>>(x, cb, idx, out, partial);
    finalize_kernel<<<dim3(1), dim3(256), 0, stream>>>(partial, out + NTOT);
}

// Round 3
// 215.525 us; speedup vs baseline: 3.1270x; 3.1270x over previous
//
#include <hip/hip_runtime.h>

#define BATCH 64
#define DIM 256
#define HW 1024
#define N_POS 65536
#define K_CODES 1024
#define NTOT 16777216

typedef __bf16 bf16x8 __attribute__((ext_vector_type(8)));
typedef float f32x4 __attribute__((ext_vector_type(4)));

__device__ inline unsigned short f2bf(float f) {   // RNE f32->bf16 (inputs are normal)
    unsigned int u = __builtin_bit_cast(unsigned int, f);
    unsigned int r = u + 0x7FFFu + ((u >> 16) & 1u);
    return (unsigned short)(r >> 16);
}
__device__ inline float bf2f(unsigned short u) {
    unsigned int x = ((unsigned int)u) << 16;
    return __builtin_bit_cast(float, x);
}

// ---------------------------------------------------------------------------
// Kernel 0: cbt[k][d] = bf16(cb[k][d]) row-major; cnorm[k] = 0.5*||bf16(c_k)||^2
__global__ void cbprep_kernel(const float* __restrict__ cb, unsigned short* __restrict__ cbt,
                              float* __restrict__ cnorm) {
    const int wv = threadIdx.x >> 6, lane = threadIdx.x & 63;
    const int k = blockIdx.x * 4 + wv;                 // grid 256
    const float4 v = *reinterpret_cast<const float4*>(cb + (size_t)k * DIM + lane * 4);
    ushort4 pk;
    pk.x = f2bf(v.x); pk.y = f2bf(v.y); pk.z = f2bf(v.z); pk.w = f2bf(v.w);
    *reinterpret_cast<ushort4*>(cbt + (size_t)k * DIM + lane * 4) = pk;
    const float f0 = bf2f(pk.x), f1 = bf2f(pk.y), f2 = bf2f(pk.z), f3 = bf2f(pk.w);
    float s = f0 * f0 + f1 * f1 + f2 * f2 + f3 * f3;
    #pragma unroll
    for (int off = 32; off; off >>= 1) s += __shfl_xor(s, off);
    if (lane == 0) cnorm[k] = 0.5f * s;
}

// ---------------------------------------------------------------------------
// Kernel 1: transpose+convert: xt[b*1024+p][d] = bf16(x[b][d][p])
// Block: 64 positions (one b), LDS tile ts[64 p][256 d] bf16, XOR-swizzled.
__global__ __launch_bounds__(256) void transpose_kernel(
        const float* __restrict__ x, unsigned short* __restrict__ xt) {
    __shared__ unsigned char ts[64 * 512];
    const int tid = threadIdx.x;
    const int b  = blockIdx.x >> 4;                    // grid 1024
    const int p0 = (blockIdx.x & 15) << 6;
    const float* xb = x + (size_t)b * (DIM * HW) + p0;
    const int p4 = tid & 15;                           // float4 index over 64 p
    const int dh = tid >> 4;                           // 0..15 -> d pair
    #pragma unroll
    for (int dp = 0; dp < 8; ++dp) {
        const int d0 = dp * 32 + dh * 2;
        const float4 v0 = *reinterpret_cast<const float4*>(xb + (size_t)d0 * HW + p4 * 4);
        const float4 v1 = *reinterpret_cast<const float4*>(xb + (size_t)(d0 + 1) * HW + p4 * 4);
        const float a0[4] = {v0.x, v0.y, v0.z, v0.w};
        const float a1[4] = {v1.x, v1.y, v1.z, v1.w};
        #pragma unroll
        for (int e = 0; e < 4; ++e) {
            const int p = p4 * 4 + e;
            const unsigned int pk = (unsigned int)f2bf(a0[e]) | ((unsigned int)f2bf(a1[e]) << 16);
            const int col = (d0 * 2) ^ ((p & 7) << 4);   // 4B-aligned, XOR bits 4-6
            *reinterpret_cast<unsigned int*>(&ts[p * 512 + col]) = pk;
        }
    }
    __syncthreads();
    const int ck = tid & 31;
    const int pr = tid >> 5;
    unsigned char* xt8 = (unsigned char*)xt;
    #pragma unroll
    for (int pp = 0; pp < 8; ++pp) {
        const int p = pp * 8 + pr;
        const uint4 v = *reinterpret_cast<const uint4*>(&ts[p * 512 + ((ck * 16) ^ ((p & 7) << 4))]);
        *reinterpret_cast<uint4*>(xt8 + (((size_t)(b * HW + p0 + p)) << 9) + ck * 16) = v;
    }
}

// ---------------------------------------------------------------------------
// Kernel 2: MFMA scoring + fused argmin.
// Block: 128 positions, 256 threads = 4 waves (2 wr x 2 wc). xs staged once via
// global_load_lds with source pre-swizzle (read-side XOR = ((pos&7)<<4)).
// B-fragments read directly from L2-resident cbt. acc over kk accumulates (C-in/out).
__global__ __launch_bounds__(256, 2) void score_kernel(
        const unsigned short* __restrict__ xt, const unsigned short* __restrict__ cbt,
        const float* __restrict__ cnorm, int* __restrict__ idx_out) {
    __shared__ unsigned char xs[64 * 1024];            // 128 pos x 512B (bf16 d row)
    const int tid = threadIdx.x;
    const int l = tid & 63, w = tid >> 6;
    const int n0 = blockIdx.x * 128;                   // grid 512
    const unsigned char* cbt8 = (const unsigned char*)cbt;

    {   // stage x tile: 16 x (64 lanes x 16B) per wave
        const unsigned char* xt8 = (const unsigned char*)xt;
        #pragma unroll
        for (int it = 0; it < 16; ++it) {
            const int X = w * 1024 + it * 4096 + l * 16;
            const int pos = X >> 9, col = X & 511;
            const unsigned char* src = xt8 + ((size_t)(n0 + pos) << 9) + (col ^ ((pos & 7) << 4));
            __builtin_amdgcn_global_load_lds(
                (const __attribute__((address_space(1))) void*)src,
                (__attribute__((address_space(3))) void*)(&xs[w * 1024 + it * 4096]),
                16, 0, 0);
        }
    }
    __syncthreads();

    const int wr = w >> 1, wc = w & 1;
    const int g = l >> 4, ln = l & 15;
    const int posbase = wr * 64;

    float bestv[16];
    int   besti[16];
    #pragma unroll
    for (int i = 0; i < 16; ++i) { bestv[i] = -3.0e38f; besti[i] = 0; }

    #pragma unroll 1
    for (int kt = 0; kt < 8; ++kt) {
        const int c0 = kt * 128 + wc * 64;
        f32x4 acc[4][4];
        #pragma unroll
        for (int mf = 0; mf < 4; ++mf)
            #pragma unroll
            for (int nf = 0; nf < 4; ++nf)
                acc[mf][nf] = (f32x4){0.f, 0.f, 0.f, 0.f};
        #pragma unroll 2
        for (int kk = 0; kk < 8; ++kk) {
            bf16x8 af[4], bfr[4];
            #pragma unroll
            for (int mf = 0; mf < 4; ++mf) {
                const int pos = posbase + mf * 16 + ln;
                const int colb = (kk * 64 + g * 16) ^ ((pos & 7) << 4);
                af[mf] = *reinterpret_cast<const bf16x8*>(&xs[pos * 512 + colb]);
            }
            #pragma unroll
            for (int nf = 0; nf < 4; ++nf) {
                const int code = c0 + nf * 16 + ln;
                bfr[nf] = *reinterpret_cast<const bf16x8*>(
                    cbt8 + ((size_t)code << 9) + kk * 64 + g * 16);
            }
            #pragma unroll
            for (int mf = 0; mf < 4; ++mf)
                #pragma unroll
                for (int nf = 0; nf < 4; ++nf)
                    acc[mf][nf] = __builtin_amdgcn_mfma_f32_16x16x32_bf16(
                        af[mf], bfr[nf], acc[mf][nf], 0, 0, 0);
        }
        // epilogue: score = dot - cnorm; per-lane best (codes ascending -> strict >)
        #pragma unroll
        for (int nf = 0; nf < 4; ++nf) {
            const int k = c0 + nf * 16 + ln;
            const float cn = cnorm[k];
            #pragma unroll
            for (int mf = 0; mf < 4; ++mf)
                #pragma unroll
                for (int r = 0; r < 4; ++r) {
                    const float s = acc[mf][nf][r] - cn;
                    const int slot = mf * 4 + r;
                    if (s > bestv[slot]) { bestv[slot] = s; besti[slot] = k; }
                }
        }
    }

    // cross-lane reduce over ln (lanes sharing g cover same positions)
    #pragma unroll
    for (int off = 1; off < 16; off <<= 1) {
        #pragma unroll
        for (int slot = 0; slot < 16; ++slot) {
            const float ov = __shfl_xor(bestv[slot], off);
            const int   oi = __shfl_xor(besti[slot], off);
            if (ov > bestv[slot] || (ov == bestv[slot] && oi < besti[slot])) {
                bestv[slot] = ov; besti[slot] = oi;
            }
        }
    }
    // merge the two wc waves via LDS (xs reuse), then write
    __syncthreads();                                    // all xs reads done
    float* rv = (float*)xs;                             // [2 wr][64 pos]
    int*   ri = (int*)(xs + 512);
    if (wc == 1 && ln == 0) {
        #pragma unroll
        for (int mf = 0; mf < 4; ++mf)
            #pragma unroll
            for (int r = 0; r < 4; ++r) {
                const int pl = mf * 16 + g * 4 + r;
                rv[wr * 64 + pl] = bestv[mf * 4 + r];
                ri[wr * 64 + pl] = besti[mf * 4 + r];
            }
    }
    __syncthreads();
    if (wc == 0 && ln == 0) {
        #pragma unroll
        for (int mf = 0; mf < 4; ++mf)
            #pragma unroll
            for (int r = 0; r < 4; ++r) {
                const int pl = mf * 16 + g * 4 + r;
                float bv = bestv[mf * 4 + r];
                int   bi = besti[mf * 4 + r];
                const float ov = rv[wr * 64 + pl];
                const int   oi = ri[wr * 64 + pl];
                if (ov > bv || (ov == bv && oi < bi)) { bv = ov; bi = oi; }
                idx_out[n0 + wr * 64 + pl] = bi;
            }
    }
}

// ---------------------------------------------------------------------------
// Kernel 3: gather + quantize + fused (x-q)^2 partial sums (f32 codebook)
__global__ __launch_bounds__(256) void quantize_kernel(
        const float* __restrict__ x, const float* __restrict__ cb,
        const int* __restrict__ idx, float* __restrict__ out,
        float* __restrict__ partial) {
    const int blk = blockIdx.x;        // grid 1024
    const int n0 = blk * 64;
    const int b  = n0 >> 10;
    const int p0 = n0 & 1023;
    const int lane = threadIdx.x & 63;
    const int w    = threadIdx.x >> 6;
    const int ci = idx[n0 + lane];
    const float4* cbrow4 = reinterpret_cast<const float4*>(cb + (size_t)ci * DIM);
    const size_t base = (size_t)b * DIM * HW + p0 + lane;

    float s = 0.0f;
    #pragma unroll
    for (int dq = 0; dq < 16; ++dq) {
        const float4 cq = cbrow4[w * 16 + dq];
        const int dbase = w * 64 + dq * 4;
        const float qv[4] = {cq.x, cq.y, cq.z, cq.w};
        #pragma unroll
        for (int e = 0; e < 4; ++e) {
            const int d = dbase + e;
            const float xv = x[base + (size_t)d * HW];
            out[base + (size_t)d * HW] = qv[e];
            const float diff = xv - qv[e];
            s = fmaf(diff, diff, s);
        }
    }
    #pragma unroll
    for (int off = 32; off; off >>= 1) s += __shfl_xor(s, off);
    __shared__ float wsum[4];
    if (lane == 0) wsum[w] = s;
    __syncthreads();
    if (threadIdx.x == 0) partial[blk] = wsum[0] + wsum[1] + wsum[2] + wsum[3];
}

// ---------------------------------------------------------------------------
__global__ void finalize_kernel(const float* __restrict__ partial, float* __restrict__ out_loss) {
    float s = 0.0f;
    for (int i = threadIdx.x; i < 1024; i += 256) s += partial[i];
    #pragma unroll
    for (int off = 32; off; off >>= 1) s += __shfl_xor(s, off);
    __shared__ float wsum[4];
    if ((threadIdx.x & 63) == 0) wsum[threadIdx.x >> 6] = s;
    __syncthreads();
    if (threadIdx.x == 0)
        out_loss[0] = 1.25f * (wsum[0] + wsum[1] + wsum[2] + wsum[3]) / (float)NTOT;
}

// ---------------------------------------------------------------------------
extern "C" void kernel_launch(void* const* d_in, const int* in_sizes, int n_in,
                              void* d_out, int out_size, void* d_ws, size_t ws_size,
                              hipStream_t stream) {
    const float* x  = (const float*)d_in[0];   // [64,256,32,32]
    const float* cb = (const float*)d_in[1];   // [1024,256]
    float* out = (float*)d_out;                // [16777216] + [1 loss]

    // Big intermediates live in d_out (overwritten by quantize at the end):
    //   xt  : 65536*256 bf16 = 32 MB at out[0]
    //   cbt : 1024*256  bf16 = 512 KB after xt
    unsigned short* xt  = (unsigned short*)d_out;
    unsigned short* cbt = xt + (size_t)N_POS * DIM;
    // ws: idx[65536] ints | partial[1024] f32 | cnorm[1024] f32  (264 KB)
    int*   idx     = (int*)d_ws;
    float* partial = (float*)((char*)d_ws + 262144);
    float* cnorm   = (float*)((char*)d_ws + 262144 + 4096);

    cbprep_kernel  <<<dim3(256),  dim3(256), 0, stream>>>(cb, cbt, cnorm);
    transpose_kernel<<<dim3(1024), dim3(256), 0, stream>>>(x, xt);
    score_kernel   <<<dim3(512),  dim3(256), 0, stream>>>(xt, cbt, cnorm, idx);
    quantize_kernel<<<dim3(1024), dim3(256), 0, stream>>>(x, cb, idx, out, partial);
    finalize_kernel<<<dim3(1),    dim3(256), 0, stream>>>(partial, out + NTOT);
}